// Round 7
// baseline (59.132 us; speedup 1.0000x reference)
//
#include <hip/hip_runtime.h>
#include <hip/hip_bf16.h>

// Problem constants (match reference)
#define T_TOK 8192
#define DDIM  1024
#define HDIM  512
#define NE    8
#define TPE   (T_TOK / NE)   // 1024 tokens per expert (static partition per reference)

typedef __attribute__((ext_vector_type(4))) float floatx4;
typedef __attribute__((ext_vector_type(8))) short bf16x8;

__device__ __forceinline__ unsigned short f2bf(float f) {
    union { float f; unsigned int u; } v;
    v.f = f;
    unsigned int u = v.u;
    unsigned int r = u + 0x7FFFu + ((u >> 16) & 1u);  // RNE
    return (unsigned short)(r >> 16);
}

// async global -> LDS, 16 bytes per lane (dest must be linear: base + lane*16)
__device__ __forceinline__ void gld_lds16(const void* g, void* l) {
    __builtin_amdgcn_global_load_lds(
        (const __attribute__((address_space(1))) unsigned int*)g,
        (__attribute__((address_space(3))) unsigned int*)l, 16, 0, 0);
}

// ---------------------------------------------------------------------------
// Kernel 0 (streaming): W13 fp32->bf16, W2 fp32->bf16, X*scale -> bf16.
// ---------------------------------------------------------------------------
__global__ __launch_bounds__(256)
void convert_kernel(const float* __restrict__ X, const float* __restrict__ S,
                    const float* __restrict__ W13, const float* __restrict__ W2,
                    unsigned short* __restrict__ Xb,
                    unsigned short* __restrict__ W13b,
                    unsigned short* __restrict__ W2b)
{
    const int NTX  = (T_TOK * DDIM) / 4;           // 2,097,152 float4 chunks
    const int NT13 = (NE * 2 * HDIM * DDIM) / 4;   // 2,097,152
    const int NT2  = (NE * DDIM * HDIM) / 4;       // 1,048,576
    const int stride = gridDim.x * blockDim.x;
    for (int i = blockIdx.x * blockDim.x + threadIdx.x; i < NTX + NT13 + NT2; i += stride) {
        float4 v;
        ushort4* dst;
        if (i < NTX) {
            int row = i >> 8;            // D/4 = 256 chunks per row
            int c4  = i & 255;
            v = reinterpret_cast<const float4*>(X)[i];
            float sc = S[row * (DDIM / 32) + (c4 >> 3)];
            v.x *= sc; v.y *= sc; v.z *= sc; v.w *= sc;
            dst = (ushort4*)Xb + i;
        } else if (i < NTX + NT13) {
            int j = i - NTX;
            v = reinterpret_cast<const float4*>(W13)[j];
            dst = (ushort4*)W13b + j;
        } else {
            int j = i - NTX - NT13;
            v = reinterpret_cast<const float4*>(W2)[j];
            dst = (ushort4*)W2b + j;
        }
        ushort4 b;
        b.x = f2bf(v.x); b.y = f2bf(v.y); b.z = f2bf(v.z); b.w = f2bf(v.w);
        *dst = b;
    }
}

// XCD-aware swizzle for 512-block grids (512 % 8 == 0 -> bijective):
// each XCD gets a contiguous chunk of 64 logical blocks (= one expert).
__device__ __forceinline__ int xcd_swizzle_512(int raw) {
    return (raw & 7) * 64 + (raw >> 3);
}

// LDS tile layout: [128 rows][8 slots of 16B]. Bank-conflict swizzle (T2/G21):
//   LDS dest stays LINEAR (global_load_lds requirement);
//   global SOURCE slot is pre-permuted: src_slot = dst_slot ^ (row & 7);
//   ds_read column applies the same XOR: phys_slot = log_slot ^ (row & 7).
// Read pattern (16 rows x same slot) then spreads over 8 slots -> 2-way (free).

// ---------------------------------------------------------------------------
// Kernel 1: h = silu(Xb W1^T) * (Xb W3^T). Pure bf16, gld_lds both operands.
// Tile: M=128 tokens x 64 h-cols (paired w1+w3 => 128 B rows), BK=64, K=1024.
// Double-buffered LDS + prefetch-next-tile + counted vmcnt(8).
// Block order within an XCD/expert: nt-major (mt fastest) -> consecutive
// blocks share a 256 KB W13b slice and keep the 2 MB Xb expert slice
// L2-resident (rotating working set ~2.25 MB < 4 MB per-XCD L2).
// 4 waves 2x2; grid = 512, LDS 64 KB -> 2 blocks/CU.
// ---------------------------------------------------------------------------
__global__ __launch_bounds__(256, 2)
void gemm1_silu_kernel(const unsigned short* __restrict__ Xb,
                       const unsigned short* __restrict__ W13b,
                       __hip_bfloat16* __restrict__ Hout)
{
    const int bid = xcd_swizzle_512(blockIdx.x);
    const int e  = bid >> 6;
    const int nt = (bid >> 3) & 7;    // h tile (64 cols)   -- nt-major
    const int mt = bid & 7;           // token tile (128 rows) -- fastest
    const int tok0 = e * TPE + mt * 128;
    const unsigned short* __restrict__ We = W13b + (size_t)e * (2 * HDIM) * DDIM;

    __shared__ __hip_bfloat16 sA[2][128][64];
    __shared__ __hip_bfloat16 sB[2][128][64];

    const int tid  = threadIdx.x;
    const int lane = tid & 63;
    const int wave = tid >> 6;
    const int wr = wave >> 1;   // 0..1 (M half)
    const int wc = wave & 1;    // 0..1 (N: 32 cols each)
    const int lr = lane & 15;
    // swizzled read column base: phys_slot(ks) = (sw0 ^ (ks<<2)) ; col = slot*8
    const int sw0 = ((lane >> 4) ^ (lane & 7));

    floatx4 acc1[4][2] = {};
    floatx4 acc3[4][2] = {};

    // staging geometry: LDS dest linear (row = tid>>3, slot = tid&7);
    // global source slot pre-swizzled by row&7.
    const int srow0 = (tid >> 3);                               // 0..31
    const int dcol  = (tid & 7) * 8;                            // LDS dest col
    const int gcol  = ((tid & 7) ^ (srow0 & 7)) * 8;            // global src col

    auto STAGE = [&](int kk, int buf) {
        const int k0 = kk * 64;
        #pragma unroll
        for (int j = 0; j < 4; ++j) {
            int row = srow0 + j * 32;   // j*32 keeps row&7 constant
            gld_lds16(&Xb[(size_t)(tok0 + row) * DDIM + k0 + gcol],
                      &sA[buf][row][dcol]);
            int wrow = (j < 2) ? (nt * 64 + row)                    // w1 rows
                               : (HDIM + nt * 64 + (row - 64));     // w3 rows
            gld_lds16(&We[(size_t)wrow * DDIM + k0 + gcol],
                      &sB[buf][row][dcol]);
        }
    };
    auto COMPUTE = [&](int buf) {
        #pragma unroll
        for (int ks = 0; ks < 2; ++ks) {
            const int rc = (sw0 ^ (ks << 2)) << 3;   // swizzled read col (elems)
            bf16x8 a[4], b1[2], b3[2];
            #pragma unroll
            for (int m = 0; m < 4; ++m)
                a[m] = *reinterpret_cast<const bf16x8*>(&sA[buf][wr * 64 + m * 16 + lr][rc]);
            #pragma unroll
            for (int n = 0; n < 2; ++n) {
                b1[n] = *reinterpret_cast<const bf16x8*>(&sB[buf][wc * 32 + n * 16 + lr][rc]);
                b3[n] = *reinterpret_cast<const bf16x8*>(&sB[buf][64 + wc * 32 + n * 16 + lr][rc]);
            }
            #pragma unroll
            for (int m = 0; m < 4; ++m)
                #pragma unroll
                for (int n = 0; n < 2; ++n) {
                    acc1[m][n] = __builtin_amdgcn_mfma_f32_16x16x32_bf16(a[m], b1[n], acc1[m][n], 0, 0, 0);
                    acc3[m][n] = __builtin_amdgcn_mfma_f32_16x16x32_bf16(a[m], b3[n], acc3[m][n], 0, 0, 0);
                }
        }
    };

    STAGE(0, 0);
    for (int kk = 0; kk < DDIM / 64 - 1; ++kk) {       // kk = 0..14
        STAGE(kk + 1, (kk + 1) & 1);
        asm volatile("s_waitcnt vmcnt(8)" ::: "memory");  // current tile landed
        __builtin_amdgcn_sched_barrier(0);
        __builtin_amdgcn_s_barrier();
        COMPUTE(kk & 1);
        __builtin_amdgcn_s_barrier();                  // guard buf before next STAGE
    }
    asm volatile("s_waitcnt vmcnt(0)" ::: "memory");
    __builtin_amdgcn_sched_barrier(0);
    __builtin_amdgcn_s_barrier();
    COMPUTE(1);                                        // tile 15

    // ---- epilogue: h = silu(h1) * h3 -> bf16
    const int hcol0 = nt * 64 + wc * 32;
    #pragma unroll
    for (int m = 0; m < 4; ++m) {
        #pragma unroll
        for (int n = 0; n < 2; ++n) {
            #pragma unroll
            for (int i = 0; i < 4; ++i) {
                int row = tok0 + wr * 64 + m * 16 + (lane >> 4) * 4 + i;
                int col = hcol0 + n * 16 + (lane & 15);
                float h1 = acc1[m][n][i];
                float h3 = acc3[m][n][i];
                float sig = 1.0f / (1.0f + __expf(-h1));
                Hout[(size_t)row * HDIM + col] = __float2bfloat16(h1 * sig * h3);
            }
        }
    }
}

// ---------------------------------------------------------------------------
// Kernel 2: out = h W2^T. All-bf16, gld_lds, same prefetch + swizzle.
// Working set per XCD (Hb 1 MB + W2b 1 MB) fits L2; order unchanged.
// Tile 128x128, BK=64, K=512 (8 K-steps). grid = 512, LDS 64 KB.
// ---------------------------------------------------------------------------
__global__ __launch_bounds__(256, 2)
void gemm2_kernel(const __hip_bfloat16* __restrict__ Hin,
                  const unsigned short* __restrict__ W2b,
                  float* __restrict__ Out)
{
    const int bid = xcd_swizzle_512(blockIdx.x);
    const int e  = bid >> 6;
    const int mt = (bid >> 3) & 7;
    const int nt = bid & 7;
    const int tok0 = e * TPE + mt * 128;
    const unsigned short* __restrict__ We = W2b + (size_t)e * DDIM * HDIM;

    __shared__ __hip_bfloat16 sA[2][128][64];
    __shared__ __hip_bfloat16 sB[2][128][64];

    const int tid  = threadIdx.x;
    const int lane = tid & 63;
    const int wave = tid >> 6;
    const int wr = wave >> 1;
    const int wc = wave & 1;
    const int lr = lane & 15;
    const int sw0 = ((lane >> 4) ^ (lane & 7));

    floatx4 acc[4][4] = {};

    const int srow0 = (tid >> 3);
    const int dcol  = (tid & 7) * 8;
    const int gcol  = ((tid & 7) ^ (srow0 & 7)) * 8;

    auto STAGE = [&](int kk, int buf) {
        const int k0 = kk * 64;
        #pragma unroll
        for (int j = 0; j < 4; ++j) {
            int row = srow0 + j * 32;
            gld_lds16(&Hin[(size_t)(tok0 + row) * HDIM + k0 + gcol],
                      &sA[buf][row][dcol]);
            gld_lds16(&We[(size_t)(nt * 128 + row) * HDIM + k0 + gcol],
                      &sB[buf][row][dcol]);
        }
    };
    auto COMPUTE = [&](int buf) {
        #pragma unroll
        for (int ks = 0; ks < 2; ++ks) {
            const int rc = (sw0 ^ (ks << 2)) << 3;
            bf16x8 a[4], b[4];
            #pragma unroll
            for (int m = 0; m < 4; ++m)
                a[m] = *reinterpret_cast<const bf16x8*>(&sA[buf][wr * 64 + m * 16 + lr][rc]);
            #pragma unroll
            for (int n = 0; n < 4; ++n)
                b[n] = *reinterpret_cast<const bf16x8*>(&sB[buf][wc * 64 + n * 16 + lr][rc]);
            #pragma unroll
            for (int m = 0; m < 4; ++m)
                #pragma unroll
                for (int n = 0; n < 4; ++n)
                    acc[m][n] = __builtin_amdgcn_mfma_f32_16x16x32_bf16(a[m], b[n], acc[m][n], 0, 0, 0);
        }
    };

    STAGE(0, 0);
    for (int kk = 0; kk < HDIM / 64 - 1; ++kk) {       // kk = 0..6
        STAGE(kk + 1, (kk + 1) & 1);
        asm volatile("s_waitcnt vmcnt(8)" ::: "memory");
        __builtin_amdgcn_sched_barrier(0);
        __builtin_amdgcn_s_barrier();
        COMPUTE(kk & 1);
        __builtin_amdgcn_s_barrier();
    }
    asm volatile("s_waitcnt vmcnt(0)" ::: "memory");
    __builtin_amdgcn_sched_barrier(0);
    __builtin_amdgcn_s_barrier();
    COMPUTE(1);                                        // tile 7

    const int dcol0 = nt * 128 + wc * 64;
    #pragma unroll
    for (int m = 0; m < 4; ++m) {
        #pragma unroll
        for (int n = 0; n < 4; ++n) {
            #pragma unroll
            for (int i = 0; i < 4; ++i) {
                int row = tok0 + wr * 64 + m * 16 + (lane >> 4) * 4 + i;
                int col = dcol0 + n * 16 + (lane & 15);
                Out[(size_t)row * DDIM + col] = acc[m][n][i];
            }
        }
    }
}

extern "C" void kernel_launch(void* const* d_in, const int* in_sizes, int n_in,
                              void* d_out, int out_size, void* d_ws, size_t ws_size,
                              hipStream_t stream) {
    const float* X   = (const float*)d_in[0];   // (T, D) fp32
    const float* S   = (const float*)d_in[1];   // (T, D/32) fp32
    const float* W13 = (const float*)d_in[4];   // (E, 2H, D) fp32
    const float* W2  = (const float*)d_in[5];   // (E, D, H) fp32
    float* Out = (float*)d_out;                 // (T, D) fp32

    // workspace layout (bytes):
    //   [0, 16Mi)    W13b bf16 (E*2H*D)
    //   [16Mi, 24Mi) W2b  bf16 (E*D*H)
    //   [24Mi, 32Mi) Hb   bf16 (T*H)
    // Xb (T*D bf16 = 16 MiB) lives in d_out's first half: gemm1 consumes it,
    // then gemm2 overwrites all of d_out with the final fp32 output.
    unsigned short* W13b = (unsigned short*)d_ws;
    unsigned short* W2b  = W13b + (size_t)NE * 2 * HDIM * DDIM;
    __hip_bfloat16* Hb   = (__hip_bfloat16*)(W2b + (size_t)NE * DDIM * HDIM);
    unsigned short* Xb   = (unsigned short*)d_out;

    convert_kernel<<<2048, 256, 0, stream>>>(X, S, W13, W2, Xb, W13b, W2b);
    gemm1_silu_kernel<<<NE * 8 * 8, 256, 0, stream>>>(Xb, W13b, Hb);
    gemm2_kernel<<<NE * 8 * 8, 256, 0, stream>>>(Hb, W2b, Out);
}

// Round 8
// 58.051 us; speedup vs baseline: 1.0186x; 1.0186x over previous
//
#include <hip/hip_runtime.h>
#include <hip/hip_bf16.h>

// Problem constants (match reference)
#define T_TOK 8192
#define DDIM  1024
#define HDIM  512
#define NE    8
#define TPE   (T_TOK / NE)   // 1024 tokens per expert (static partition per reference)

typedef __attribute__((ext_vector_type(4))) float floatx4;
typedef __attribute__((ext_vector_type(8))) short bf16x8;

__device__ __forceinline__ unsigned short f2bf(float f) {
    union { float f; unsigned int u; } v;
    v.f = f;
    unsigned int u = v.u;
    unsigned int r = u + 0x7FFFu + ((u >> 16) & 1u);  // RNE
    return (unsigned short)(r >> 16);
}

// packed f32x2 -> bf16x2 (RNE), single instruction
__device__ __forceinline__ unsigned int cvt_pk_bf16(float lo, float hi) {
    unsigned int r;
    asm("v_cvt_pk_bf16_f32 %0, %1, %2" : "=v"(r) : "v"(lo), "v"(hi));
    return r;
}

// async global -> LDS, 16 bytes per lane (dest must be linear: base + lane*16)
__device__ __forceinline__ void gld_lds16(const void* g, void* l) {
    __builtin_amdgcn_global_load_lds(
        (const __attribute__((address_space(1))) unsigned int*)g,
        (__attribute__((address_space(3))) unsigned int*)l, 16, 0, 0);
}

// ---------------------------------------------------------------------------
// Kernel 0 (streaming): W13 fp32 -> bf16 only (80 MB round trip).
// X-dequant and W2 conversion are fused into the GEMMs' staging.
// ---------------------------------------------------------------------------
__global__ __launch_bounds__(256)
void convert_w13_kernel(const float* __restrict__ W13,
                        unsigned short* __restrict__ W13b)
{
    const int NT13 = (NE * 2 * HDIM * DDIM) / 4;   // 2,097,152 float4 chunks
    const int stride = gridDim.x * blockDim.x;
    for (int i = blockIdx.x * blockDim.x + threadIdx.x; i < NT13; i += stride) {
        float4 v = reinterpret_cast<const float4*>(W13)[i];
        ushort4 b;
        b.x = f2bf(v.x); b.y = f2bf(v.y); b.z = f2bf(v.z); b.w = f2bf(v.w);
        reinterpret_cast<ushort4*>(W13b)[i] = b;
    }
}

// XCD-aware swizzle for 512-block grids (512 % 8 == 0 -> bijective):
// each XCD gets a contiguous chunk of 64 logical blocks (= one expert).
__device__ __forceinline__ int xcd_swizzle_512(int raw) {
    return (raw & 7) * 64 + (raw >> 3);
}

// LDS tile layout: [128 rows][8 slots of 16B]. Bank-conflict swizzle (T2/G21):
//   phys_slot = logical_slot ^ (row & 7)  (involution within each 128B row)
//   - gld_lds path: LDS dest LINEAR, global SOURCE slot pre-permuted.
//   - reg-staged path: ds_write directly to the swizzled slot.
//   - ds_read applies the same XOR.

// ---------------------------------------------------------------------------
// Kernel 1: h = silu(X W1^T) * (X W3^T).
// A = X*scale fp32->bf16 REG-STAGED (load->cvt_pk->swizzled ds_write);
// B = W13b bf16 via gld_lds (linear dest, pre-swizzled source).
// Tile M=128 x N=64 h-cols (w1+w3 paired => 128 B rows), BK=64, 16 K-steps.
// Double-buffered, counted vmcnt: per iter issue order is fixed
// [LOADA 12 VM ops][STAGEB 4 VM ops]; vmcnt(4) frees rA, vmcnt(16) covers B.
// Order: mt-major (nt fastest) -> X tile (512 KB fp32) L2-resident, W13b
// streamed (rotating ~2.5 MB < 4 MB per-XCD L2).
// ---------------------------------------------------------------------------
__global__ __launch_bounds__(256, 2)
void gemm1_silu_kernel(const float* __restrict__ X,
                       const float* __restrict__ S,
                       const unsigned short* __restrict__ W13b,
                       __hip_bfloat16* __restrict__ Hout)
{
    const int bid = xcd_swizzle_512(blockIdx.x);
    const int e  = bid >> 6;
    const int mt = (bid >> 3) & 7;    // token tile (128 rows) -- major
    const int nt = bid & 7;           // h tile (64 cols)      -- fastest
    const int tok0 = e * TPE + mt * 128;
    const unsigned short* __restrict__ We = W13b + (size_t)e * (2 * HDIM) * DDIM;

    __shared__ __hip_bfloat16 sA[2][128][64];
    __shared__ __hip_bfloat16 sB[2][128][64];

    const int tid  = threadIdx.x;
    const int lane = tid & 63;
    const int wave = tid >> 6;
    const int wr = wave >> 1;   // 0..1 (M half)
    const int wc = wave & 1;    // 0..1 (N: 32 cols each)
    const int lr = lane & 15;
    const int sw0 = ((lane >> 4) ^ (lane & 7));

    floatx4 acc1[4][2] = {};
    floatx4 acc3[4][2] = {};

    // staging geometry: thread owns (row = tid>>3 [+32k], slot = tid&7)
    const int srow0 = (tid >> 3);                       // 0..31
    const int c8    = (tid & 7) * 8;                    // logical col chunk
    const int dcol  = (tid & 7) * 8;                    // B LDS linear dest
    const int swcol = ((tid & 7) ^ (srow0 & 7)) * 8;    // swizzled slot (A write, B src)

    float4 rA[8]; float rs[4];

    auto LOADA = [&](int kk) {              // 12 VM ops (8 dwordx4 + 4 dword)
        const int k0 = kk * 64;
        #pragma unroll
        for (int j = 0; j < 4; ++j) {
            int row = srow0 + j * 32;
            const float* p = &X[(size_t)(tok0 + row) * DDIM + k0 + c8];
            rA[2*j]   = *reinterpret_cast<const float4*>(p);
            rA[2*j+1] = *reinterpret_cast<const float4*>(p + 4);
            rs[j] = S[(size_t)(tok0 + row) * (DDIM / 32) + ((k0 + c8) >> 5)];
        }
    };
    auto STAGEB = [&](int kk, int buf) {    // 4 VM ops (gld_lds)
        const int k0 = kk * 64;
        #pragma unroll
        for (int j = 0; j < 4; ++j) {
            int row = srow0 + j * 32;       // row&7 invariant under +32
            int wrow = (j < 2) ? (nt * 64 + row)                    // w1 rows
                               : (HDIM + nt * 64 + (row - 64));     // w3 rows
            gld_lds16(&We[(size_t)wrow * DDIM + k0 + swcol],
                      &sB[buf][row][dcol]);
        }
    };
    auto WRITEA = [&](int buf) {            // cvt + swizzled ds_write_b128
        #pragma unroll
        for (int j = 0; j < 4; ++j) {
            int row = srow0 + j * 32;
            float sc = rs[j];
            uint4 w;
            w.x = cvt_pk_bf16(rA[2*j].x * sc,   rA[2*j].y * sc);
            w.y = cvt_pk_bf16(rA[2*j].z * sc,   rA[2*j].w * sc);
            w.z = cvt_pk_bf16(rA[2*j+1].x * sc, rA[2*j+1].y * sc);
            w.w = cvt_pk_bf16(rA[2*j+1].z * sc, rA[2*j+1].w * sc);
            *reinterpret_cast<uint4*>(&sA[buf][row][swcol]) = w;
        }
    };
    auto COMPUTE = [&](int buf) {
        #pragma unroll
        for (int ks = 0; ks < 2; ++ks) {
            const int rc = (sw0 ^ (ks << 2)) << 3;   // swizzled read col
            bf16x8 a[4], b1[2], b3[2];
            #pragma unroll
            for (int m = 0; m < 4; ++m)
                a[m] = *reinterpret_cast<const bf16x8*>(&sA[buf][wr * 64 + m * 16 + lr][rc]);
            #pragma unroll
            for (int n = 0; n < 2; ++n) {
                b1[n] = *reinterpret_cast<const bf16x8*>(&sB[buf][wc * 32 + n * 16 + lr][rc]);
                b3[n] = *reinterpret_cast<const bf16x8*>(&sB[buf][64 + wc * 32 + n * 16 + lr][rc]);
            }
            #pragma unroll
            for (int m = 0; m < 4; ++m)
                #pragma unroll
                for (int n = 0; n < 2; ++n) {
                    acc1[m][n] = __builtin_amdgcn_mfma_f32_16x16x32_bf16(a[m], b1[n], acc1[m][n], 0, 0, 0);
                    acc3[m][n] = __builtin_amdgcn_mfma_f32_16x16x32_bf16(a[m], b3[n], acc3[m][n], 0, 0, 0);
                }
        }
    };

    LOADA(0);
    __builtin_amdgcn_sched_barrier(0);
    STAGEB(0, 0);
    __builtin_amdgcn_sched_barrier(0);
    for (int kk = 0; kk < DDIM / 64 - 1; ++kk) {          // kk = 0..14
        const int buf = kk & 1;
        asm volatile("s_waitcnt vmcnt(4)" ::: "memory");  // rA(kk) landed
        __builtin_amdgcn_sched_barrier(0);
        WRITEA(buf);
        __builtin_amdgcn_sched_barrier(0);
        LOADA(kk + 1);
        __builtin_amdgcn_sched_barrier(0);
        STAGEB(kk + 1, buf ^ 1);
        __builtin_amdgcn_sched_barrier(0);
        asm volatile("s_waitcnt vmcnt(16) lgkmcnt(0)" ::: "memory"); // B(kk)+A-writes done
        __builtin_amdgcn_sched_barrier(0);
        __builtin_amdgcn_s_barrier();
        COMPUTE(buf);
        __builtin_amdgcn_s_barrier();
    }
    asm volatile("s_waitcnt vmcnt(4)" ::: "memory");      // rA(15) landed
    __builtin_amdgcn_sched_barrier(0);
    WRITEA(1);
    asm volatile("s_waitcnt vmcnt(0) lgkmcnt(0)" ::: "memory");
    __builtin_amdgcn_sched_barrier(0);
    __builtin_amdgcn_s_barrier();
    COMPUTE(1);                                           // tile 15

    // ---- epilogue: h = silu(h1) * h3 -> bf16
    const int hcol0 = nt * 64 + wc * 32;
    #pragma unroll
    for (int m = 0; m < 4; ++m) {
        #pragma unroll
        for (int n = 0; n < 2; ++n) {
            #pragma unroll
            for (int i = 0; i < 4; ++i) {
                int row = tok0 + wr * 64 + m * 16 + (lane >> 4) * 4 + i;
                int col = hcol0 + n * 16 + (lane & 15);
                float h1 = acc1[m][n][i];
                float h3 = acc3[m][n][i];
                float sig = 1.0f / (1.0f + __expf(-h1));
                Hout[(size_t)row * HDIM + col] = __float2bfloat16(h1 * sig * h3);
            }
        }
    }
}

// ---------------------------------------------------------------------------
// Kernel 2: out = h W2^T.
// A = Hb bf16 via gld_lds; B = W2 fp32->bf16 REG-STAGED (fused convert).
// Tile 128x128, BK=64, 8 K-steps. Issue order [LOADB 8][STAGEA 4];
// vmcnt(4) frees rB, vmcnt(12) covers A. Order: nt-major (mt fastest) ->
// W2 tile (256 KB fp32) L2-resident, Hb slice re-read from L2.
// ---------------------------------------------------------------------------
__global__ __launch_bounds__(256, 2)
void gemm2_kernel(const __hip_bfloat16* __restrict__ Hin,
                  const float* __restrict__ W2,
                  float* __restrict__ Out)
{
    const int bid = xcd_swizzle_512(blockIdx.x);
    const int e  = bid >> 6;
    const int nt = (bid >> 3) & 7;    // d tile -- major (W2 tile reused)
    const int mt = bid & 7;           // token tile -- fastest (stream Hb)
    const int tok0 = e * TPE + mt * 128;
    const float* __restrict__ We = W2 + (size_t)e * DDIM * HDIM;

    __shared__ __hip_bfloat16 sA[2][128][64];
    __shared__ __hip_bfloat16 sB[2][128][64];

    const int tid  = threadIdx.x;
    const int lane = tid & 63;
    const int wave = tid >> 6;
    const int wr = wave >> 1;
    const int wc = wave & 1;
    const int lr = lane & 15;
    const int sw0 = ((lane >> 4) ^ (lane & 7));

    floatx4 acc[4][4] = {};

    const int srow0 = (tid >> 3);
    const int c8    = (tid & 7) * 8;
    const int dcol  = (tid & 7) * 8;
    const int swcol = ((tid & 7) ^ (srow0 & 7)) * 8;

    float4 rB[8];

    auto LOADB = [&](int kk) {              // 8 VM ops
        const int k0 = kk * 64;
        #pragma unroll
        for (int j = 0; j < 4; ++j) {
            int row = srow0 + j * 32;
            const float* p = &We[(size_t)(nt * 128 + row) * HDIM + k0 + c8];
            rB[2*j]   = *reinterpret_cast<const float4*>(p);
            rB[2*j+1] = *reinterpret_cast<const float4*>(p + 4);
        }
    };
    auto STAGEA = [&](int kk, int buf) {    // 4 VM ops (gld_lds)
        const int k0 = kk * 64;
        #pragma unroll
        for (int j = 0; j < 4; ++j) {
            int row = srow0 + j * 32;
            gld_lds16(&Hin[(size_t)(tok0 + row) * HDIM + k0 + swcol],
                      &sA[buf][row][dcol]);
        }
    };
    auto WRITEB = [&](int buf) {
        #pragma unroll
        for (int j = 0; j < 4; ++j) {
            int row = srow0 + j * 32;
            uint4 w;
            w.x = cvt_pk_bf16(rB[2*j].x,   rB[2*j].y);
            w.y = cvt_pk_bf16(rB[2*j].z,   rB[2*j].w);
            w.z = cvt_pk_bf16(rB[2*j+1].x, rB[2*j+1].y);
            w.w = cvt_pk_bf16(rB[2*j+1].z, rB[2*j+1].w);
            *reinterpret_cast<uint4*>(&sB[buf][row][swcol]) = w;
        }
    };
    auto COMPUTE = [&](int buf) {
        #pragma unroll
        for (int ks = 0; ks < 2; ++ks) {
            const int rc = (sw0 ^ (ks << 2)) << 3;
            bf16x8 a[4], b[4];
            #pragma unroll
            for (int m = 0; m < 4; ++m)
                a[m] = *reinterpret_cast<const bf16x8*>(&sA[buf][wr * 64 + m * 16 + lr][rc]);
            #pragma unroll
            for (int n = 0; n < 4; ++n)
                b[n] = *reinterpret_cast<const bf16x8*>(&sB[buf][wc * 64 + n * 16 + lr][rc]);
            #pragma unroll
            for (int m = 0; m < 4; ++m)
                #pragma unroll
                for (int n = 0; n < 4; ++n)
                    acc[m][n] = __builtin_amdgcn_mfma_f32_16x16x32_bf16(a[m], b[n], acc[m][n], 0, 0, 0);
        }
    };

    LOADB(0);
    __builtin_amdgcn_sched_barrier(0);
    STAGEA(0, 0);
    __builtin_amdgcn_sched_barrier(0);
    for (int kk = 0; kk < HDIM / 64 - 1; ++kk) {          // kk = 0..6
        const int buf = kk & 1;
        asm volatile("s_waitcnt vmcnt(4)" ::: "memory");  // rB(kk) landed
        __builtin_amdgcn_sched_barrier(0);
        WRITEB(buf);
        __builtin_amdgcn_sched_barrier(0);
        LOADB(kk + 1);
        __builtin_amdgcn_sched_barrier(0);
        STAGEA(kk + 1, buf ^ 1);
        __builtin_amdgcn_sched_barrier(0);
        asm volatile("s_waitcnt vmcnt(12) lgkmcnt(0)" ::: "memory"); // A(kk)+B-writes done
        __builtin_amdgcn_sched_barrier(0);
        __builtin_amdgcn_s_barrier();
        COMPUTE(buf);
        __builtin_amdgcn_s_barrier();
    }
    asm volatile("s_waitcnt vmcnt(4)" ::: "memory");      // rB(7) landed
    __builtin_amdgcn_sched_barrier(0);
    WRITEB(1);
    asm volatile("s_waitcnt vmcnt(0) lgkmcnt(0)" ::: "memory");
    __builtin_amdgcn_sched_barrier(0);
    __builtin_amdgcn_s_barrier();
    COMPUTE(1);                                           // tile 7

    const int dcol0 = nt * 128 + wc * 64;
    #pragma unroll
    for (int m = 0; m < 4; ++m) {
        #pragma unroll
        for (int n = 0; n < 4; ++n) {
            #pragma unroll
            for (int i = 0; i < 4; ++i) {
                int row = tok0 + wr * 64 + m * 16 + (lane >> 4) * 4 + i;
                int col = dcol0 + n * 16 + (lane & 15);
                Out[(size_t)row * DDIM + col] = acc[m][n][i];
            }
        }
    }
}

extern "C" void kernel_launch(void* const* d_in, const int* in_sizes, int n_in,
                              void* d_out, int out_size, void* d_ws, size_t ws_size,
                              hipStream_t stream) {
    const float* X   = (const float*)d_in[0];   // (T, D) fp32
    const float* S   = (const float*)d_in[1];   // (T, D/32) fp32
    const float* W13 = (const float*)d_in[4];   // (E, 2H, D) fp32
    const float* W2  = (const float*)d_in[5];   // (E, D, H) fp32
    float* Out = (float*)d_out;                 // (T, D) fp32

    // workspace layout (bytes):
    //   [0, 16Mi)    W13b bf16 (E*2H*D)
    //   [16Mi, 24Mi) Hb   bf16 (T*H)
    unsigned short* W13b = (unsigned short*)d_ws;
    __hip_bfloat16* Hb   = (__hip_bfloat16*)(W13b + (size_t)NE * 2 * HDIM * DDIM);

    convert_w13_kernel<<<2048, 256, 0, stream>>>(W13, W13b);
    gemm1_silu_kernel<<<NE * 8 * 8, 256, 0, stream>>>(X, S, W13b, Hb);
    gemm2_kernel<<<NE * 8 * 8, 256, 0, stream>>>(Hb, W2, Out);
}

// Round 9
// 57.595 us; speedup vs baseline: 1.0267x; 1.0079x over previous
//
#include <hip/hip_runtime.h>
#include <hip/hip_bf16.h>

// Problem constants (match reference)
#define T_TOK 8192
#define DDIM  1024
#define HDIM  512
#define NE    8
#define TPE   (T_TOK / NE)   // 1024 tokens per expert (static partition per reference)

typedef __attribute__((ext_vector_type(4))) float floatx4;
typedef __attribute__((ext_vector_type(8))) short bf16x8;

__device__ __forceinline__ unsigned short f2bf(float f) {
    union { float f; unsigned int u; } v;
    v.f = f;
    unsigned int u = v.u;
    unsigned int r = u + 0x7FFFu + ((u >> 16) & 1u);  // RNE
    return (unsigned short)(r >> 16);
}

// packed f32x2 -> bf16x2 (RNE), single instruction
__device__ __forceinline__ unsigned int cvt_pk_bf16(float lo, float hi) {
    unsigned int r;
    asm("v_cvt_pk_bf16_f32 %0, %1, %2" : "=v"(r) : "v"(lo), "v"(hi));
    return r;
}

// async global -> LDS, 16 bytes per lane (dest must be linear: base + lane*16)
__device__ __forceinline__ void gld_lds16(const void* g, void* l) {
    __builtin_amdgcn_global_load_lds(
        (const __attribute__((address_space(1))) unsigned int*)g,
        (__attribute__((address_space(3))) unsigned int*)l, 16, 0, 0);
}

// ---------------------------------------------------------------------------
// Kernel 0 (streaming): X*scale -> bf16 and W13 fp32 -> bf16.
// (W2's conversion is fused into gemm2's B staging.)
// ---------------------------------------------------------------------------
__global__ __launch_bounds__(256)
void convert_kernel(const float* __restrict__ X, const float* __restrict__ S,
                    const float* __restrict__ W13,
                    unsigned short* __restrict__ Xb,
                    unsigned short* __restrict__ W13b)
{
    const int NTX  = (T_TOK * DDIM) / 4;           // 2,097,152 float4 chunks
    const int NT13 = (NE * 2 * HDIM * DDIM) / 4;   // 2,097,152
    const int stride = gridDim.x * blockDim.x;
    for (int i = blockIdx.x * blockDim.x + threadIdx.x; i < NTX + NT13; i += stride) {
        float4 v;
        ushort4* dst;
        if (i < NTX) {
            int row = i >> 8;            // D/4 = 256 chunks per row
            int c4  = i & 255;
            v = reinterpret_cast<const float4*>(X)[i];
            float sc = S[row * (DDIM / 32) + (c4 >> 3)];
            v.x *= sc; v.y *= sc; v.z *= sc; v.w *= sc;
            dst = (ushort4*)Xb + i;
        } else {
            int j = i - NTX;
            v = reinterpret_cast<const float4*>(W13)[j];
            dst = (ushort4*)W13b + j;
        }
        ushort4 b;
        b.x = f2bf(v.x); b.y = f2bf(v.y); b.z = f2bf(v.z); b.w = f2bf(v.w);
        *dst = b;
    }
}

// XCD-aware swizzle for 512-block grids (512 % 8 == 0 -> bijective):
// each XCD gets a contiguous chunk of 64 logical blocks (= one expert).
__device__ __forceinline__ int xcd_swizzle_512(int raw) {
    return (raw & 7) * 64 + (raw >> 3);
}

// LDS tile layout: [128 rows][8 slots of 16B]. Bank-conflict swizzle (T2/G21):
//   phys_slot = logical_slot ^ (row & 7)  (involution within each 128B row)
//   - gld_lds path: LDS dest LINEAR, global SOURCE slot pre-permuted.
//   - reg-staged path: ds_write directly to the swizzled slot.
//   - ds_read applies the same XOR.

// ---------------------------------------------------------------------------
// Kernel 1: h = silu(Xb W1^T) * (Xb W3^T). Pure bf16, gld_lds both operands.
// Tile: M=128 tokens x 64 h-cols (paired w1+w3 => 128 B rows), BK=64, K=1024.
// Double-buffered LDS + prefetch-next-tile + counted vmcnt(8).
// 4 waves 2x2; grid = 512, LDS 64 KB -> 2 blocks/CU.  (round-6 form, ~20us)
// ---------------------------------------------------------------------------
__global__ __launch_bounds__(256, 2)
void gemm1_silu_kernel(const unsigned short* __restrict__ Xb,
                       const unsigned short* __restrict__ W13b,
                       __hip_bfloat16* __restrict__ Hout)
{
    const int bid = xcd_swizzle_512(blockIdx.x);
    const int e  = bid >> 6;
    const int mt = (bid >> 3) & 7;    // token tile (128 rows)
    const int nt = bid & 7;           // h tile (64 cols)
    const int tok0 = e * TPE + mt * 128;
    const unsigned short* __restrict__ We = W13b + (size_t)e * (2 * HDIM) * DDIM;

    __shared__ __hip_bfloat16 sA[2][128][64];
    __shared__ __hip_bfloat16 sB[2][128][64];

    const int tid  = threadIdx.x;
    const int lane = tid & 63;
    const int wave = tid >> 6;
    const int wr = wave >> 1;   // 0..1 (M half)
    const int wc = wave & 1;    // 0..1 (N: 32 cols each)
    const int lr = lane & 15;
    const int sw0 = ((lane >> 4) ^ (lane & 7));

    floatx4 acc1[4][2] = {};
    floatx4 acc3[4][2] = {};

    // staging geometry: LDS dest linear (row = tid>>3, slot = tid&7);
    // global source slot pre-swizzled by row&7.
    const int srow0 = (tid >> 3);                               // 0..31
    const int dcol  = (tid & 7) * 8;                            // LDS dest col
    const int gcol  = ((tid & 7) ^ (srow0 & 7)) * 8;            // global src col

    auto STAGE = [&](int kk, int buf) {
        const int k0 = kk * 64;
        #pragma unroll
        for (int j = 0; j < 4; ++j) {
            int row = srow0 + j * 32;   // j*32 keeps row&7 constant
            gld_lds16(&Xb[(size_t)(tok0 + row) * DDIM + k0 + gcol],
                      &sA[buf][row][dcol]);
            int wrow = (j < 2) ? (nt * 64 + row)                    // w1 rows
                               : (HDIM + nt * 64 + (row - 64));     // w3 rows
            gld_lds16(&We[(size_t)wrow * DDIM + k0 + gcol],
                      &sB[buf][row][dcol]);
        }
    };
    auto COMPUTE = [&](int buf) {
        #pragma unroll
        for (int ks = 0; ks < 2; ++ks) {
            const int rc = (sw0 ^ (ks << 2)) << 3;   // swizzled read col (elems)
            bf16x8 a[4], b1[2], b3[2];
            #pragma unroll
            for (int m = 0; m < 4; ++m)
                a[m] = *reinterpret_cast<const bf16x8*>(&sA[buf][wr * 64 + m * 16 + lr][rc]);
            #pragma unroll
            for (int n = 0; n < 2; ++n) {
                b1[n] = *reinterpret_cast<const bf16x8*>(&sB[buf][wc * 32 + n * 16 + lr][rc]);
                b3[n] = *reinterpret_cast<const bf16x8*>(&sB[buf][64 + wc * 32 + n * 16 + lr][rc]);
            }
            #pragma unroll
            for (int m = 0; m < 4; ++m)
                #pragma unroll
                for (int n = 0; n < 2; ++n) {
                    acc1[m][n] = __builtin_amdgcn_mfma_f32_16x16x32_bf16(a[m], b1[n], acc1[m][n], 0, 0, 0);
                    acc3[m][n] = __builtin_amdgcn_mfma_f32_16x16x32_bf16(a[m], b3[n], acc3[m][n], 0, 0, 0);
                }
        }
    };

    STAGE(0, 0);
    for (int kk = 0; kk < DDIM / 64 - 1; ++kk) {       // kk = 0..14
        STAGE(kk + 1, (kk + 1) & 1);
        asm volatile("s_waitcnt vmcnt(8)" ::: "memory");  // current tile landed
        __builtin_amdgcn_sched_barrier(0);
        __builtin_amdgcn_s_barrier();
        COMPUTE(kk & 1);
        __builtin_amdgcn_s_barrier();                  // guard buf before next STAGE
    }
    asm volatile("s_waitcnt vmcnt(0)" ::: "memory");
    __builtin_amdgcn_sched_barrier(0);
    __builtin_amdgcn_s_barrier();
    COMPUTE(1);                                        // tile 15

    // ---- epilogue: h = silu(h1) * h3 -> bf16
    const int hcol0 = nt * 64 + wc * 32;
    #pragma unroll
    for (int m = 0; m < 4; ++m) {
        #pragma unroll
        for (int n = 0; n < 2; ++n) {
            #pragma unroll
            for (int i = 0; i < 4; ++i) {
                int row = tok0 + wr * 64 + m * 16 + (lane >> 4) * 4 + i;
                int col = hcol0 + n * 16 + (lane & 15);
                float h1 = acc1[m][n][i];
                float h3 = acc3[m][n][i];
                float sig = 1.0f / (1.0f + __expf(-h1));
                Hout[(size_t)row * HDIM + col] = __float2bfloat16(h1 * sig * h3);
            }
        }
    }
}

// ---------------------------------------------------------------------------
// Kernel 2: out = h W2^T.
// A = Hb bf16 via gld_lds; B = W2 fp32->bf16 REG-STAGED (fused convert).
// Tile 128x128, BK=64, 8 K-steps. Issue order [LOADB 8][STAGEA 4];
// vmcnt(4) frees rB, vmcnt(12) covers A. Order: nt-major (mt fastest) ->
// W2 tile (256 KB fp32) L2-resident, Hb slice re-read from L2.
// (round-8 form — did not regress, eliminates W2b round trip)
// ---------------------------------------------------------------------------
__global__ __launch_bounds__(256, 2)
void gemm2_kernel(const __hip_bfloat16* __restrict__ Hin,
                  const float* __restrict__ W2,
                  float* __restrict__ Out)
{
    const int bid = xcd_swizzle_512(blockIdx.x);
    const int e  = bid >> 6;
    const int nt = (bid >> 3) & 7;    // d tile -- major (W2 tile reused)
    const int mt = bid & 7;           // token tile -- fastest (stream Hb)
    const int tok0 = e * TPE + mt * 128;
    const float* __restrict__ We = W2 + (size_t)e * DDIM * HDIM;

    __shared__ __hip_bfloat16 sA[2][128][64];
    __shared__ __hip_bfloat16 sB[2][128][64];

    const int tid  = threadIdx.x;
    const int lane = tid & 63;
    const int wave = tid >> 6;
    const int wr = wave >> 1;
    const int wc = wave & 1;
    const int lr = lane & 15;
    const int sw0 = ((lane >> 4) ^ (lane & 7));

    floatx4 acc[4][4] = {};

    const int srow0 = (tid >> 3);
    const int c8    = (tid & 7) * 8;
    const int dcol  = (tid & 7) * 8;
    const int swcol = ((tid & 7) ^ (srow0 & 7)) * 8;

    float4 rB[8];

    auto LOADB = [&](int kk) {              // 8 VM ops
        const int k0 = kk * 64;
        #pragma unroll
        for (int j = 0; j < 4; ++j) {
            int row = srow0 + j * 32;
            const float* p = &We[(size_t)(nt * 128 + row) * HDIM + k0 + c8];
            rB[2*j]   = *reinterpret_cast<const float4*>(p);
            rB[2*j+1] = *reinterpret_cast<const float4*>(p + 4);
        }
    };
    auto STAGEA = [&](int kk, int buf) {    // 4 VM ops (gld_lds)
        const int k0 = kk * 64;
        #pragma unroll
        for (int j = 0; j < 4; ++j) {
            int row = srow0 + j * 32;
            gld_lds16(&Hin[(size_t)(tok0 + row) * HDIM + k0 + swcol],
                      &sA[buf][row][dcol]);
        }
    };
    auto WRITEB = [&](int buf) {
        #pragma unroll
        for (int j = 0; j < 4; ++j) {
            int row = srow0 + j * 32;
            uint4 w;
            w.x = cvt_pk_bf16(rB[2*j].x,   rB[2*j].y);
            w.y = cvt_pk_bf16(rB[2*j].z,   rB[2*j].w);
            w.z = cvt_pk_bf16(rB[2*j+1].x, rB[2*j+1].y);
            w.w = cvt_pk_bf16(rB[2*j+1].z, rB[2*j+1].w);
            *reinterpret_cast<uint4*>(&sB[buf][row][swcol]) = w;
        }
    };
    auto COMPUTE = [&](int buf) {
        #pragma unroll
        for (int ks = 0; ks < 2; ++ks) {
            const int rc = (sw0 ^ (ks << 2)) << 3;
            bf16x8 a[4], b[4];
            #pragma unroll
            for (int m = 0; m < 4; ++m)
                a[m] = *reinterpret_cast<const bf16x8*>(&sA[buf][wr * 64 + m * 16 + lr][rc]);
            #pragma unroll
            for (int n = 0; n < 4; ++n)
                b[n] = *reinterpret_cast<const bf16x8*>(&sB[buf][wc * 64 + n * 16 + lr][rc]);
            #pragma unroll
            for (int m = 0; m < 4; ++m)
                #pragma unroll
                for (int n = 0; n < 4; ++n)
                    acc[m][n] = __builtin_amdgcn_mfma_f32_16x16x32_bf16(a[m], b[n], acc[m][n], 0, 0, 0);
        }
    };

    LOADB(0);
    __builtin_amdgcn_sched_barrier(0);
    STAGEA(0, 0);
    __builtin_amdgcn_sched_barrier(0);
    for (int kk = 0; kk < HDIM / 64 - 1; ++kk) {          // kk = 0..6
        const int buf = kk & 1;
        asm volatile("s_waitcnt vmcnt(4)" ::: "memory");  // rB(kk) landed
        __builtin_amdgcn_sched_barrier(0);
        WRITEB(buf);
        __builtin_amdgcn_sched_barrier(0);
        LOADB(kk + 1);
        __builtin_amdgcn_sched_barrier(0);
        STAGEA(kk + 1, buf ^ 1);
        __builtin_amdgcn_sched_barrier(0);
        asm volatile("s_waitcnt vmcnt(12) lgkmcnt(0)" ::: "memory"); // A(kk)+B-writes done
        __builtin_amdgcn_sched_barrier(0);
        __builtin_amdgcn_s_barrier();
        COMPUTE(buf);
        __builtin_amdgcn_s_barrier();
    }
    asm volatile("s_waitcnt vmcnt(4)" ::: "memory");      // rB(7) landed
    __builtin_amdgcn_sched_barrier(0);
    WRITEB(1);
    asm volatile("s_waitcnt vmcnt(0) lgkmcnt(0)" ::: "memory");
    __builtin_amdgcn_sched_barrier(0);
    __builtin_amdgcn_s_barrier();
    COMPUTE(1);                                           // tile 7

    const int dcol0 = nt * 128 + wc * 64;
    #pragma unroll
    for (int m = 0; m < 4; ++m) {
        #pragma unroll
        for (int n = 0; n < 4; ++n) {
            #pragma unroll
            for (int i = 0; i < 4; ++i) {
                int row = tok0 + wr * 64 + m * 16 + (lane >> 4) * 4 + i;
                int col = dcol0 + n * 16 + (lane & 15);
                Out[(size_t)row * DDIM + col] = acc[m][n][i];
            }
        }
    }
}

extern "C" void kernel_launch(void* const* d_in, const int* in_sizes, int n_in,
                              void* d_out, int out_size, void* d_ws, size_t ws_size,
                              hipStream_t stream) {
    const float* X   = (const float*)d_in[0];   // (T, D) fp32
    const float* S   = (const float*)d_in[1];   // (T, D/32) fp32
    const float* W13 = (const float*)d_in[4];   // (E, 2H, D) fp32
    const float* W2  = (const float*)d_in[5];   // (E, D, H) fp32
    float* Out = (float*)d_out;                 // (T, D) fp32

    // workspace layout (bytes):
    //   [0, 16Mi)    W13b bf16 (E*2H*D)
    //   [16Mi, 24Mi) Hb   bf16 (T*H)
    // Xb (T*D bf16 = 16 MiB) lives in d_out's first half: gemm1 consumes it,
    // then gemm2 overwrites all of d_out with the final fp32 output.
    unsigned short* W13b = (unsigned short*)d_ws;
    __hip_bfloat16* Hb   = (__hip_bfloat16*)(W13b + (size_t)NE * 2 * HDIM * DDIM);
    unsigned short* Xb   = (unsigned short*)d_out;

    convert_kernel<<<2048, 256, 0, stream>>>(X, S, W13, Xb, W13b);
    gemm1_silu_kernel<<<NE * 8 * 8, 256, 0, stream>>>(Xb, W13b, Hb);
    gemm2_kernel<<<NE * 8 * 8, 256, 0, stream>>>(Hb, W2, Out);
}

// Round 10
// 56.112 us; speedup vs baseline: 1.0538x; 1.0264x over previous
//
#include <hip/hip_runtime.h>
#include <hip/hip_bf16.h>

// Problem constants (match reference)
#define T_TOK 8192
#define DDIM  1024
#define HDIM  512
#define NE    8
#define TPE   (T_TOK / NE)   // 1024 tokens per expert (static partition per reference)

typedef __attribute__((ext_vector_type(4))) float floatx4;
typedef __attribute__((ext_vector_type(8))) short bf16x8;

__device__ __forceinline__ unsigned short f2bf(float f) {
    union { float f; unsigned int u; } v;
    v.f = f;
    unsigned int u = v.u;
    unsigned int r = u + 0x7FFFu + ((u >> 16) & 1u);  // RNE
    return (unsigned short)(r >> 16);
}

// packed f32x2 -> bf16x2 (RNE), single instruction
__device__ __forceinline__ unsigned int cvt_pk_bf16(float lo, float hi) {
    unsigned int r;
    asm("v_cvt_pk_bf16_f32 %0, %1, %2" : "=v"(r) : "v"(lo), "v"(hi));
    return r;
}

// async global -> LDS, 16 bytes per lane (dest must be linear: base + lane*16)
__device__ __forceinline__ void gld_lds16(const void* g, void* l) {
    __builtin_amdgcn_global_load_lds(
        (const __attribute__((address_space(1))) unsigned int*)g,
        (__attribute__((address_space(3))) unsigned int*)l, 16, 0, 0);
}

// ---------------------------------------------------------------------------
// Kernel 0 (streaming): X*scale -> bf16 only (48 MB round trip).
// W13 and W2 conversions are fused into the GEMMs' B staging.
// ---------------------------------------------------------------------------
__global__ __launch_bounds__(256)
void convert_x_kernel(const float* __restrict__ X, const float* __restrict__ S,
                      unsigned short* __restrict__ Xb)
{
    const int NTX = (T_TOK * DDIM) / 4;            // 2,097,152 float4 chunks
    const int stride = gridDim.x * blockDim.x;
    for (int i = blockIdx.x * blockDim.x + threadIdx.x; i < NTX; i += stride) {
        int row = i >> 8;            // D/4 = 256 chunks per row
        int c4  = i & 255;
        float4 v = reinterpret_cast<const float4*>(X)[i];
        float sc = S[row * (DDIM / 32) + (c4 >> 3)];
        ushort4 b;
        b.x = f2bf(v.x * sc); b.y = f2bf(v.y * sc);
        b.z = f2bf(v.z * sc); b.w = f2bf(v.w * sc);
        reinterpret_cast<ushort4*>(Xb)[i] = b;
    }
}

// XCD-aware swizzle for 512-block grids (512 % 8 == 0 -> bijective):
// each XCD gets a contiguous chunk of 64 logical blocks (= one expert).
__device__ __forceinline__ int xcd_swizzle_512(int raw) {
    return (raw & 7) * 64 + (raw >> 3);
}

// LDS tile layout: [128 rows][8 slots of 16B]. Bank-conflict swizzle (T2/G21):
//   phys_slot = logical_slot ^ (row & 7)  (involution within each 128B row)
//   - gld_lds path: LDS dest LINEAR, global SOURCE slot pre-permuted.
//   - reg-staged path: ds_write directly to the swizzled slot.
//   - ds_read applies the same XOR.

// ---------------------------------------------------------------------------
// Kernel 1: h = silu(Xb W1^T) * (Xb W3^T).
// A = Xb bf16 via gld_lds; B = W13 fp32 REG-STAGED with DEPTH-2 prefetch
// (two named rB buffers, even/odd-unrolled loop -> static indexing),
// cvt_pk -> swizzled ds_write. Steady-state: one vmcnt(12)+lgkmcnt(0)/step.
// Tile M=128 x N=64 h-cols (w1+w3 paired => 128 B rows), BK=64, 16 K-steps.
// 4 waves 2x2; grid = 512, LDS 64 KB -> 2 blocks/CU.
// ---------------------------------------------------------------------------
__global__ __launch_bounds__(256, 2)
void gemm1_silu_kernel(const unsigned short* __restrict__ Xb,
                       const float* __restrict__ W13,
                       __hip_bfloat16* __restrict__ Hout)
{
    const int bid = xcd_swizzle_512(blockIdx.x);
    const int e  = bid >> 6;
    const int mt = (bid >> 3) & 7;    // token tile (128 rows)
    const int nt = bid & 7;           // h tile (64 cols)
    const int tok0 = e * TPE + mt * 128;
    const float* __restrict__ We = W13 + (size_t)e * (2 * HDIM) * DDIM;

    __shared__ __hip_bfloat16 sA[2][128][64];
    __shared__ __hip_bfloat16 sB[2][128][64];

    const int tid  = threadIdx.x;
    const int lane = tid & 63;
    const int wave = tid >> 6;
    const int wr = wave >> 1;   // 0..1 (M half)
    const int wc = wave & 1;    // 0..1 (N: 32 cols each)
    const int lr = lane & 15;
    const int sw0 = ((lane >> 4) ^ (lane & 7));

    floatx4 acc1[4][2] = {};
    floatx4 acc3[4][2] = {};

    // staging geometry
    const int srow0 = (tid >> 3);                       // 0..31
    const int c8    = (tid & 7) * 8;                    // logical col chunk
    const int dcol  = (tid & 7) * 8;                    // A LDS linear dest
    const int gcol  = ((tid & 7) ^ (srow0 & 7)) * 8;    // A global pre-swz src
    const int swcol = gcol;                             // B swizzled ds_write slot

    float4 rB0[8], rB1[8];

    auto LOADB = [&](int kk, float4* rB) {   // 8 VM ops, fp32 W13 (w1|w3 rows)
        const int k0 = kk * 64;
        #pragma unroll
        for (int j = 0; j < 4; ++j) {
            int row = srow0 + j * 32;
            int wrow = (j < 2) ? (nt * 64 + row)                 // w1 rows
                               : (HDIM + nt * 64 + (row - 64));  // w3 rows
            const float* p = &We[(size_t)wrow * DDIM + k0 + c8];
            rB[2*j]   = *reinterpret_cast<const float4*>(p);
            rB[2*j+1] = *reinterpret_cast<const float4*>(p + 4);
        }
    };
    auto STAGEA = [&](int kk, int buf) {     // 4 VM ops (gld_lds)
        const int k0 = kk * 64;
        #pragma unroll
        for (int j = 0; j < 4; ++j) {
            int row = srow0 + j * 32;        // row&7 invariant under +32
            gld_lds16(&Xb[(size_t)(tok0 + row) * DDIM + k0 + gcol],
                      &sA[buf][row][dcol]);
        }
    };
    auto WRITEB = [&](int buf, const float4* rB) {   // cvt + swizzled ds_write
        #pragma unroll
        for (int j = 0; j < 4; ++j) {
            int row = srow0 + j * 32;
            uint4 w;
            w.x = cvt_pk_bf16(rB[2*j].x,   rB[2*j].y);
            w.y = cvt_pk_bf16(rB[2*j].z,   rB[2*j].w);
            w.z = cvt_pk_bf16(rB[2*j+1].x, rB[2*j+1].y);
            w.w = cvt_pk_bf16(rB[2*j+1].z, rB[2*j+1].w);
            *reinterpret_cast<uint4*>(&sB[buf][row][swcol]) = w;
        }
    };
    auto COMPUTE = [&](int buf) {
        #pragma unroll
        for (int ks = 0; ks < 2; ++ks) {
            const int rc = (sw0 ^ (ks << 2)) << 3;   // swizzled read col
            bf16x8 a[4], b1[2], b3[2];
            #pragma unroll
            for (int m = 0; m < 4; ++m)
                a[m] = *reinterpret_cast<const bf16x8*>(&sA[buf][wr * 64 + m * 16 + lr][rc]);
            #pragma unroll
            for (int n = 0; n < 2; ++n) {
                b1[n] = *reinterpret_cast<const bf16x8*>(&sB[buf][wc * 32 + n * 16 + lr][rc]);
                b3[n] = *reinterpret_cast<const bf16x8*>(&sB[buf][64 + wc * 32 + n * 16 + lr][rc]);
            }
            #pragma unroll
            for (int m = 0; m < 4; ++m)
                #pragma unroll
                for (int n = 0; n < 2; ++n) {
                    acc1[m][n] = __builtin_amdgcn_mfma_f32_16x16x32_bf16(a[m], b1[n], acc1[m][n], 0, 0, 0);
                    acc3[m][n] = __builtin_amdgcn_mfma_f32_16x16x32_bf16(a[m], b3[n], acc3[m][n], 0, 0, 0);
                }
        }
    };

    // ---- prologue: tiles 0,1 -> regs; tile 0 A -> LDS; wait for rB0 only
    LOADB(0, rB0);
    __builtin_amdgcn_sched_barrier(0);
    LOADB(1, rB1);
    __builtin_amdgcn_sched_barrier(0);
    STAGEA(0, 0);
    __builtin_amdgcn_sched_barrier(0);
    asm volatile("s_waitcnt vmcnt(12)" ::: "memory");   // rB(0) landed
    __builtin_amdgcn_sched_barrier(0);

    // ---- main loop: kk = 0..13, two K-steps per iteration (static rB names)
    for (int t = 0; t < DDIM / 64 - 2; t += 2) {        // t = 0,2,...,12
        // even step kk=t, buf 0: rB0 holds tile t (guaranteed by prev wait)
        WRITEB(0, rB0);
        __builtin_amdgcn_sched_barrier(0);
        LOADB(t + 2, rB0);                              // WAR-safe: in-order issue
        __builtin_amdgcn_sched_barrier(0);
        STAGEA(t + 1, 1);
        __builtin_amdgcn_sched_barrier(0);
        asm volatile("s_waitcnt vmcnt(12) lgkmcnt(0)" ::: "memory"); // LOADB(t+1)+STAGEA(t) done
        __builtin_amdgcn_sched_barrier(0);
        __builtin_amdgcn_s_barrier();
        COMPUTE(0);
        __builtin_amdgcn_s_barrier();
        // odd step kk=t+1, buf 1
        WRITEB(1, rB1);
        __builtin_amdgcn_sched_barrier(0);
        LOADB(t + 3, rB1);
        __builtin_amdgcn_sched_barrier(0);
        STAGEA(t + 2, 0);
        __builtin_amdgcn_sched_barrier(0);
        asm volatile("s_waitcnt vmcnt(12) lgkmcnt(0)" ::: "memory"); // LOADB(t+2)+STAGEA(t+1) done
        __builtin_amdgcn_sched_barrier(0);
        __builtin_amdgcn_s_barrier();
        COMPUTE(1);
        __builtin_amdgcn_s_barrier();
    }

    // ---- tail: kk = 14 (buf 0), kk = 15 (buf 1); no more loads
    WRITEB(0, rB0);                                     // rB(14)
    __builtin_amdgcn_sched_barrier(0);
    STAGEA(15, 1);
    __builtin_amdgcn_sched_barrier(0);
    asm volatile("s_waitcnt vmcnt(4) lgkmcnt(0)" ::: "memory");  // LOADB(15)+STAGEA(14) done
    __builtin_amdgcn_sched_barrier(0);
    __builtin_amdgcn_s_barrier();
    COMPUTE(0);
    __builtin_amdgcn_s_barrier();
    WRITEB(1, rB1);                                     // rB(15)
    __builtin_amdgcn_sched_barrier(0);
    asm volatile("s_waitcnt vmcnt(0) lgkmcnt(0)" ::: "memory");  // STAGEA(15) done
    __builtin_amdgcn_sched_barrier(0);
    __builtin_amdgcn_s_barrier();
    COMPUTE(1);

    // ---- epilogue: h = silu(h1) * h3 -> bf16
    const int hcol0 = nt * 64 + wc * 32;
    #pragma unroll
    for (int m = 0; m < 4; ++m) {
        #pragma unroll
        for (int n = 0; n < 2; ++n) {
            #pragma unroll
            for (int i = 0; i < 4; ++i) {
                int row = tok0 + wr * 64 + m * 16 + (lane >> 4) * 4 + i;
                int col = hcol0 + n * 16 + (lane & 15);
                float h1 = acc1[m][n][i];
                float h3 = acc3[m][n][i];
                float sig = 1.0f / (1.0f + __expf(-h1));
                Hout[(size_t)row * HDIM + col] = __float2bfloat16(h1 * sig * h3);
            }
        }
    }
}

// ---------------------------------------------------------------------------
// Kernel 2: out = h W2^T.
// A = Hb bf16 via gld_lds; B = W2 fp32->bf16 REG-STAGED (fused convert).
// Tile 128x128, BK=64, 8 K-steps. Issue order [LOADB 8][STAGEA 4];
// vmcnt(4) frees rB, vmcnt(12) covers A. nt-major: W2 tile L2-resident.
// (round-8/9 form — proven)
// ---------------------------------------------------------------------------
__global__ __launch_bounds__(256, 2)
void gemm2_kernel(const __hip_bfloat16* __restrict__ Hin,
                  const float* __restrict__ W2,
                  float* __restrict__ Out)
{
    const int bid = xcd_swizzle_512(blockIdx.x);
    const int e  = bid >> 6;
    const int nt = (bid >> 3) & 7;    // d tile -- major (W2 tile reused)
    const int mt = bid & 7;           // token tile -- fastest (stream Hb)
    const int tok0 = e * TPE + mt * 128;
    const float* __restrict__ We = W2 + (size_t)e * DDIM * HDIM;

    __shared__ __hip_bfloat16 sA[2][128][64];
    __shared__ __hip_bfloat16 sB[2][128][64];

    const int tid  = threadIdx.x;
    const int lane = tid & 63;
    const int wave = tid >> 6;
    const int wr = wave >> 1;
    const int wc = wave & 1;
    const int lr = lane & 15;
    const int sw0 = ((lane >> 4) ^ (lane & 7));

    floatx4 acc[4][4] = {};

    const int srow0 = (tid >> 3);
    const int c8    = (tid & 7) * 8;
    const int dcol  = (tid & 7) * 8;
    const int swcol = ((tid & 7) ^ (srow0 & 7)) * 8;

    float4 rB[8];

    auto LOADB = [&](int kk) {              // 8 VM ops
        const int k0 = kk * 64;
        #pragma unroll
        for (int j = 0; j < 4; ++j) {
            int row = srow0 + j * 32;
            const float* p = &We[(size_t)(nt * 128 + row) * HDIM + k0 + c8];
            rB[2*j]   = *reinterpret_cast<const float4*>(p);
            rB[2*j+1] = *reinterpret_cast<const float4*>(p + 4);
        }
    };
    auto STAGEA = [&](int kk, int buf) {    // 4 VM ops (gld_lds)
        const int k0 = kk * 64;
        #pragma unroll
        for (int j = 0; j < 4; ++j) {
            int row = srow0 + j * 32;
            gld_lds16(&Hin[(size_t)(tok0 + row) * HDIM + k0 + swcol],
                      &sA[buf][row][dcol]);
        }
    };
    auto WRITEB = [&](int buf) {
        #pragma unroll
        for (int j = 0; j < 4; ++j) {
            int row = srow0 + j * 32;
            uint4 w;
            w.x = cvt_pk_bf16(rB[2*j].x,   rB[2*j].y);
            w.y = cvt_pk_bf16(rB[2*j].z,   rB[2*j].w);
            w.z = cvt_pk_bf16(rB[2*j+1].x, rB[2*j+1].y);
            w.w = cvt_pk_bf16(rB[2*j+1].z, rB[2*j+1].w);
            *reinterpret_cast<uint4*>(&sB[buf][row][swcol]) = w;
        }
    };
    auto COMPUTE = [&](int buf) {
        #pragma unroll
        for (int ks = 0; ks < 2; ++ks) {
            const int rc = (sw0 ^ (ks << 2)) << 3;
            bf16x8 a[4], b[4];
            #pragma unroll
            for (int m = 0; m < 4; ++m)
                a[m] = *reinterpret_cast<const bf16x8*>(&sA[buf][wr * 64 + m * 16 + lr][rc]);
            #pragma unroll
            for (int n = 0; n < 4; ++n)
                b[n] = *reinterpret_cast<const bf16x8*>(&sB[buf][wc * 64 + n * 16 + lr][rc]);
            #pragma unroll
            for (int m = 0; m < 4; ++m)
                #pragma unroll
                for (int n = 0; n < 4; ++n)
                    acc[m][n] = __builtin_amdgcn_mfma_f32_16x16x32_bf16(a[m], b[n], acc[m][n], 0, 0, 0);
        }
    };

    LOADB(0);
    __builtin_amdgcn_sched_barrier(0);
    STAGEA(0, 0);
    __builtin_amdgcn_sched_barrier(0);
    for (int kk = 0; kk < HDIM / 64 - 1; ++kk) {          // kk = 0..6
        const int buf = kk & 1;
        asm volatile("s_waitcnt vmcnt(4)" ::: "memory");  // rB(kk) landed
        __builtin_amdgcn_sched_barrier(0);
        WRITEB(buf);
        __builtin_amdgcn_sched_barrier(0);
        LOADB(kk + 1);
        __builtin_amdgcn_sched_barrier(0);
        STAGEA(kk + 1, buf ^ 1);
        __builtin_amdgcn_sched_barrier(0);
        asm volatile("s_waitcnt vmcnt(12) lgkmcnt(0)" ::: "memory"); // A(kk)+B-writes done
        __builtin_amdgcn_sched_barrier(0);
        __builtin_amdgcn_s_barrier();
        COMPUTE(buf);
        __builtin_amdgcn_s_barrier();
    }
    asm volatile("s_waitcnt vmcnt(4)" ::: "memory");      // rB(7) landed
    __builtin_amdgcn_sched_barrier(0);
    WRITEB(1);
    asm volatile("s_waitcnt vmcnt(0) lgkmcnt(0)" ::: "memory");
    __builtin_amdgcn_sched_barrier(0);
    __builtin_amdgcn_s_barrier();
    COMPUTE(1);                                           // tile 7

    const int dcol0 = nt * 128 + wc * 64;
    #pragma unroll
    for (int m = 0; m < 4; ++m) {
        #pragma unroll
        for (int n = 0; n < 4; ++n) {
            #pragma unroll
            for (int i = 0; i < 4; ++i) {
                int row = tok0 + wr * 64 + m * 16 + (lane >> 4) * 4 + i;
                int col = dcol0 + n * 16 + (lane & 15);
                Out[(size_t)row * DDIM + col] = acc[m][n][i];
            }
        }
    }
}

extern "C" void kernel_launch(void* const* d_in, const int* in_sizes, int n_in,
                              void* d_out, int out_size, void* d_ws, size_t ws_size,
                              hipStream_t stream) {
    const float* X   = (const float*)d_in[0];   // (T, D) fp32
    const float* S   = (const float*)d_in[1];   // (T, D/32) fp32
    const float* W13 = (const float*)d_in[4];   // (E, 2H, D) fp32
    const float* W2  = (const float*)d_in[5];   // (E, D, H) fp32
    float* Out = (float*)d_out;                 // (T, D) fp32

    // workspace: Hb bf16 (T*H) = 8 MiB.
    // Xb (T*D bf16 = 16 MiB) lives in d_out's first half: gemm1 consumes it,
    // then gemm2 overwrites all of d_out with the final fp32 output.
    __hip_bfloat16* Hb = (__hip_bfloat16*)d_ws;
    unsigned short* Xb = (unsigned short*)d_out;

    convert_x_kernel<<<2048, 256, 0, stream>>>(X, S, Xb);
    gemm1_silu_kernel<<<NE * 8 * 8, 256, 0, stream>>>(Xb, W13, Hb);
    gemm2_kernel<<<NE * 8 * 8, 256, 0, stream>>>(Hb, W2, Out);
}

// Round 11
// 55.836 us; speedup vs baseline: 1.0590x; 1.0049x over previous
//
#include <hip/hip_runtime.h>
#include <hip/hip_bf16.h>

// Problem constants (match reference)
#define T_TOK 8192
#define DDIM  1024
#define HDIM  512
#define NE    8
#define TPE   (T_TOK / NE)   // 1024 tokens per expert (static partition per reference)

typedef __attribute__((ext_vector_type(4))) float floatx4;
typedef __attribute__((ext_vector_type(8))) short bf16x8;

#define SBAR() __builtin_amdgcn_sched_barrier(0)

__device__ __forceinline__ unsigned short f2bf(float f) {
    union { float f; unsigned int u; } v;
    v.f = f;
    unsigned int u = v.u;
    unsigned int r = u + 0x7FFFu + ((u >> 16) & 1u);  // RNE
    return (unsigned short)(r >> 16);
}

// packed f32x2 -> bf16x2 (RNE), single instruction
__device__ __forceinline__ unsigned int cvt_pk_bf16(float lo, float hi) {
    unsigned int r;
    asm("v_cvt_pk_bf16_f32 %0, %1, %2" : "=v"(r) : "v"(lo), "v"(hi));
    return r;
}

// async global -> LDS, 16 bytes per lane (dest must be linear: base + lane*16)
__device__ __forceinline__ void gld_lds16(const void* g, void* l) {
    __builtin_amdgcn_global_load_lds(
        (const __attribute__((address_space(1))) unsigned int*)g,
        (__attribute__((address_space(3))) unsigned int*)l, 16, 0, 0);
}

// ---------------------------------------------------------------------------
// Kernel 0 (streaming): X*scale -> bf16 only (48 MB round trip).
// W13 and W2 conversions are fused into the GEMMs' B staging.
// ---------------------------------------------------------------------------
__global__ __launch_bounds__(256)
void convert_x_kernel(const float* __restrict__ X, const float* __restrict__ S,
                      unsigned short* __restrict__ Xb)
{
    const int NTX = (T_TOK * DDIM) / 4;            // 2,097,152 float4 chunks
    const int stride = gridDim.x * blockDim.x;
    for (int i = blockIdx.x * blockDim.x + threadIdx.x; i < NTX; i += stride) {
        int row = i >> 8;            // D/4 = 256 chunks per row
        int c4  = i & 255;
        float4 v = reinterpret_cast<const float4*>(X)[i];
        float sc = S[row * (DDIM / 32) + (c4 >> 3)];
        ushort4 b;
        b.x = f2bf(v.x * sc); b.y = f2bf(v.y * sc);
        b.z = f2bf(v.z * sc); b.w = f2bf(v.w * sc);
        reinterpret_cast<ushort4*>(Xb)[i] = b;
    }
}

// XCD-aware swizzle for 512-block grids (512 % 8 == 0 -> bijective):
// each XCD gets a contiguous chunk of 64 logical blocks (= one expert).
__device__ __forceinline__ int xcd_swizzle_512(int raw) {
    return (raw & 7) * 64 + (raw >> 3);
}

// LDS tile layout: [128 rows][8 slots of 16B]. Bank-conflict swizzle (T2/G21):
//   phys_slot = logical_slot ^ (row & 7)  (involution within each 128B row)
//   - gld_lds path: LDS dest LINEAR, global SOURCE slot pre-permuted.
//   - reg-staged path: ds_write directly to the swizzled slot.
//   - ds_read applies the same XOR.

// ---------------------------------------------------------------------------
// Kernel 1: h = silu(Xb W1^T) * (Xb W3^T).
// A = Xb bf16 via gld_lds; B = W13 fp32 reg-staged depth-2 (rB0/rB1 static).
// ONE barrier per K-step (T3-min schedule): per phase t --
//   vmcnt(0)                       // rB(t+1) landed (full phase in flight)
//   WRITEB(t+1) -> LDS[buf^1]      // cvt_pk + swizzled ds_write
//   STAGEA(t+1) -> LDS[buf^1]      // 4 gld_lds (issued BEFORE LOADB: FIFO)
//   LOADB(t+2)  -> regs            // 8 fp32 loads, fly across barrier
//   ds_read ks0 / MFMA ks0 / ds_read ks1 / MFMA ks1   (buf)
//   vmcnt(8)                       // drains STAGEA only, LOADB stays in flight
//   s_barrier
// WAR-safe with one barrier: writes target buf^1 whose readers finished
// before the PREVIOUS barrier; ds_writes drain via FIFO lgkmcnt before MFMAs.
// 4 waves 2x2; grid = 512, LDS 64 KB -> 2 blocks/CU.
// ---------------------------------------------------------------------------
__global__ __launch_bounds__(256, 2)
void gemm1_silu_kernel(const unsigned short* __restrict__ Xb,
                       const float* __restrict__ W13,
                       __hip_bfloat16* __restrict__ Hout)
{
    const int bid = xcd_swizzle_512(blockIdx.x);
    const int e  = bid >> 6;
    const int mt = (bid >> 3) & 7;    // token tile (128 rows)
    const int nt = bid & 7;           // h tile (64 cols)
    const int tok0 = e * TPE + mt * 128;
    const float* __restrict__ We = W13 + (size_t)e * (2 * HDIM) * DDIM;

    __shared__ __hip_bfloat16 sA[2][128][64];
    __shared__ __hip_bfloat16 sB[2][128][64];

    const int tid  = threadIdx.x;
    const int lane = tid & 63;
    const int wave = tid >> 6;
    const int wr = wave >> 1;   // 0..1 (M half)
    const int wc = wave & 1;    // 0..1 (N: 32 cols each)
    const int lr = lane & 15;
    const int sw0 = ((lane >> 4) ^ (lane & 7));

    floatx4 acc1[4][2] = {};
    floatx4 acc3[4][2] = {};

    // staging geometry
    const int srow0 = (tid >> 3);                       // 0..31
    const int c8    = (tid & 7) * 8;                    // logical col chunk
    const int dcol  = (tid & 7) * 8;                    // A LDS linear dest
    const int gcol  = ((tid & 7) ^ (srow0 & 7)) * 8;    // A global pre-swz src
    const int swcol = gcol;                             // B swizzled ds_write slot

    float4 rB0[8], rB1[8];

    auto LOADB = [&](int kk, float4* rB) {   // 8 VM ops, fp32 W13 (w1|w3 rows)
        const int k0 = kk * 64;
        #pragma unroll
        for (int j = 0; j < 4; ++j) {
            int row = srow0 + j * 32;
            int wrow = (j < 2) ? (nt * 64 + row)                 // w1 rows
                               : (HDIM + nt * 64 + (row - 64));  // w3 rows
            const float* p = &We[(size_t)wrow * DDIM + k0 + c8];
            rB[2*j]   = *reinterpret_cast<const float4*>(p);
            rB[2*j+1] = *reinterpret_cast<const float4*>(p + 4);
        }
    };
    auto STAGEA = [&](int kk, int buf) {     // 4 VM ops (gld_lds)
        const int k0 = kk * 64;
        #pragma unroll
        for (int j = 0; j < 4; ++j) {
            int row = srow0 + j * 32;        // row&7 invariant under +32
            gld_lds16(&Xb[(size_t)(tok0 + row) * DDIM + k0 + gcol],
                      &sA[buf][row][dcol]);
        }
    };
    auto WRITEB = [&](int buf, const float4* rB) {   // cvt + swizzled ds_write
        #pragma unroll
        for (int j = 0; j < 4; ++j) {
            int row = srow0 + j * 32;
            uint4 w;
            w.x = cvt_pk_bf16(rB[2*j].x,   rB[2*j].y);
            w.y = cvt_pk_bf16(rB[2*j].z,   rB[2*j].w);
            w.z = cvt_pk_bf16(rB[2*j+1].x, rB[2*j+1].y);
            w.w = cvt_pk_bf16(rB[2*j+1].z, rB[2*j+1].w);
            *reinterpret_cast<uint4*>(&sB[buf][row][swcol]) = w;
        }
    };
    auto COMPUTE_KS = [&](int buf, int ks) {
        const int rc = (sw0 ^ (ks << 2)) << 3;   // swizzled read col
        bf16x8 a[4], b1[2], b3[2];
        #pragma unroll
        for (int m = 0; m < 4; ++m)
            a[m] = *reinterpret_cast<const bf16x8*>(&sA[buf][wr * 64 + m * 16 + lr][rc]);
        #pragma unroll
        for (int n = 0; n < 2; ++n) {
            b1[n] = *reinterpret_cast<const bf16x8*>(&sB[buf][wc * 32 + n * 16 + lr][rc]);
            b3[n] = *reinterpret_cast<const bf16x8*>(&sB[buf][64 + wc * 32 + n * 16 + lr][rc]);
        }
        #pragma unroll
        for (int m = 0; m < 4; ++m)
            #pragma unroll
            for (int n = 0; n < 2; ++n) {
                acc1[m][n] = __builtin_amdgcn_mfma_f32_16x16x32_bf16(a[m], b1[n], acc1[m][n], 0, 0, 0);
                acc3[m][n] = __builtin_amdgcn_mfma_f32_16x16x32_bf16(a[m], b3[n], acc3[m][n], 0, 0, 0);
            }
    };

    // ---- prologue: VM order [LOADB(0) 8][STAGEA(0) 4][LOADB(1) 8]
    LOADB(0, rB0);  SBAR();
    STAGEA(0, 0);   SBAR();
    LOADB(1, rB1);  SBAR();
    asm volatile("s_waitcnt vmcnt(8)" ::: "memory");   // LOADB(0)+STAGEA(0) done
    SBAR();
    WRITEB(0, rB0); SBAR();
    asm volatile("s_waitcnt lgkmcnt(0)" ::: "memory");
    SBAR();
    __builtin_amdgcn_s_barrier();

    // ---- main loop: phases 0..13 (even/odd pairs; static rB names)
    for (int t = 0; t < DDIM / 64 - 2; t += 2) {        // t = 0,2,...,12
        // phase t (even, buf 0): rB1 holds B(t+1)
        asm volatile("s_waitcnt vmcnt(0)" ::: "memory");  // B(t+1) regs landed
        SBAR();
        WRITEB(1, rB1);     SBAR();
        STAGEA(t + 1, 1);   SBAR();
        LOADB(t + 2, rB0);  SBAR();
        COMPUTE_KS(0, 0);
        COMPUTE_KS(0, 1);
        asm volatile("s_waitcnt vmcnt(8)" ::: "memory");  // drain STAGEA(t+1)
        SBAR();
        __builtin_amdgcn_s_barrier();
        // phase t+1 (odd, buf 1): rB0 holds B(t+2)
        asm volatile("s_waitcnt vmcnt(0)" ::: "memory");
        SBAR();
        WRITEB(0, rB0);     SBAR();
        STAGEA(t + 2, 0);   SBAR();
        LOADB(t + 3, rB1);  SBAR();
        COMPUTE_KS(1, 0);
        COMPUTE_KS(1, 1);
        asm volatile("s_waitcnt vmcnt(8)" ::: "memory");  // drain STAGEA(t+2)
        SBAR();
        __builtin_amdgcn_s_barrier();
    }

    // ---- phase 14 (buf 0): rB1 holds B(15); no more LOADB
    asm volatile("s_waitcnt vmcnt(0)" ::: "memory");
    SBAR();
    WRITEB(1, rB1);   SBAR();
    STAGEA(15, 1);    SBAR();
    COMPUTE_KS(0, 0);
    COMPUTE_KS(0, 1);
    asm volatile("s_waitcnt vmcnt(0)" ::: "memory");      // drain STAGEA(15)
    SBAR();
    __builtin_amdgcn_s_barrier();
    // ---- phase 15 (buf 1)
    COMPUTE_KS(1, 0);
    COMPUTE_KS(1, 1);

    // ---- epilogue: h = silu(h1) * h3 -> bf16
    const int hcol0 = nt * 64 + wc * 32;
    #pragma unroll
    for (int m = 0; m < 4; ++m) {
        #pragma unroll
        for (int n = 0; n < 2; ++n) {
            #pragma unroll
            for (int i = 0; i < 4; ++i) {
                int row = tok0 + wr * 64 + m * 16 + (lane >> 4) * 4 + i;
                int col = hcol0 + n * 16 + (lane & 15);
                float h1 = acc1[m][n][i];
                float h3 = acc3[m][n][i];
                float sig = 1.0f / (1.0f + __expf(-h1));
                Hout[(size_t)row * HDIM + col] = __float2bfloat16(h1 * sig * h3);
            }
        }
    }
}

// ---------------------------------------------------------------------------
// Kernel 2: out = h W2^T.
// A = Hb bf16 via gld_lds; B = W2 fp32->bf16 REG-STAGED (fused convert).
// Tile 128x128, BK=64, 8 K-steps. Issue order [LOADB 8][STAGEA 4];
// vmcnt(4) frees rB, vmcnt(12) covers A. nt-major: W2 tile L2-resident.
// (round-8/9/10 form — proven near its HBM floor; unchanged this round)
// ---------------------------------------------------------------------------
__global__ __launch_bounds__(256, 2)
void gemm2_kernel(const __hip_bfloat16* __restrict__ Hin,
                  const float* __restrict__ W2,
                  float* __restrict__ Out)
{
    const int bid = xcd_swizzle_512(blockIdx.x);
    const int e  = bid >> 6;
    const int nt = (bid >> 3) & 7;    // d tile -- major (W2 tile reused)
    const int mt = bid & 7;           // token tile -- fastest (stream Hb)
    const int tok0 = e * TPE + mt * 128;
    const float* __restrict__ We = W2 + (size_t)e * DDIM * HDIM;

    __shared__ __hip_bfloat16 sA[2][128][64];
    __shared__ __hip_bfloat16 sB[2][128][64];

    const int tid  = threadIdx.x;
    const int lane = tid & 63;
    const int wave = tid >> 6;
    const int wr = wave >> 1;
    const int wc = wave & 1;
    const int lr = lane & 15;
    const int sw0 = ((lane >> 4) ^ (lane & 7));

    floatx4 acc[4][4] = {};

    const int srow0 = (tid >> 3);
    const int c8    = (tid & 7) * 8;
    const int dcol  = (tid & 7) * 8;
    const int swcol = ((tid & 7) ^ (srow0 & 7)) * 8;

    float4 rB[8];

    auto LOADB = [&](int kk) {              // 8 VM ops
        const int k0 = kk * 64;
        #pragma unroll
        for (int j = 0; j < 4; ++j) {
            int row = srow0 + j * 32;
            const float* p = &We[(size_t)(nt * 128 + row) * HDIM + k0 + c8];
            rB[2*j]   = *reinterpret_cast<const float4*>(p);
            rB[2*j+1] = *reinterpret_cast<const float4*>(p + 4);
        }
    };
    auto STAGEA = [&](int kk, int buf) {    // 4 VM ops (gld_lds)
        const int k0 = kk * 64;
        #pragma unroll
        for (int j = 0; j < 4; ++j) {
            int row = srow0 + j * 32;
            gld_lds16(&Hin[(size_t)(tok0 + row) * HDIM + k0 + swcol],
                      &sA[buf][row][dcol]);
        }
    };
    auto WRITEB = [&](int buf) {
        #pragma unroll
        for (int j = 0; j < 4; ++j) {
            int row = srow0 + j * 32;
            uint4 w;
            w.x = cvt_pk_bf16(rB[2*j].x,   rB[2*j].y);
            w.y = cvt_pk_bf16(rB[2*j].z,   rB[2*j].w);
            w.z = cvt_pk_bf16(rB[2*j+1].x, rB[2*j+1].y);
            w.w = cvt_pk_bf16(rB[2*j+1].z, rB[2*j+1].w);
            *reinterpret_cast<uint4*>(&sB[buf][row][swcol]) = w;
        }
    };
    auto COMPUTE = [&](int buf) {
        #pragma unroll
        for (int ks = 0; ks < 2; ++ks) {
            const int rc = (sw0 ^ (ks << 2)) << 3;
            bf16x8 a[4], b[4];
            #pragma unroll
            for (int m = 0; m < 4; ++m)
                a[m] = *reinterpret_cast<const bf16x8*>(&sA[buf][wr * 64 + m * 16 + lr][rc]);
            #pragma unroll
            for (int n = 0; n < 4; ++n)
                b[n] = *reinterpret_cast<const bf16x8*>(&sB[buf][wc * 64 + n * 16 + lr][rc]);
            #pragma unroll
            for (int m = 0; m < 4; ++m)
                #pragma unroll
                for (int n = 0; n < 4; ++n)
                    acc[m][n] = __builtin_amdgcn_mfma_f32_16x16x32_bf16(a[m], b[n], acc[m][n], 0, 0, 0);
        }
    };

    LOADB(0);
    __builtin_amdgcn_sched_barrier(0);
    STAGEA(0, 0);
    __builtin_amdgcn_sched_barrier(0);
    for (int kk = 0; kk < HDIM / 64 - 1; ++kk) {          // kk = 0..6
        const int buf = kk & 1;
        asm volatile("s_waitcnt vmcnt(4)" ::: "memory");  // rB(kk) landed
        __builtin_amdgcn_sched_barrier(0);
        WRITEB(buf);
        __builtin_amdgcn_sched_barrier(0);
        LOADB(kk + 1);
        __builtin_amdgcn_sched_barrier(0);
        STAGEA(kk + 1, buf ^ 1);
        __builtin_amdgcn_sched_barrier(0);
        asm volatile("s_waitcnt vmcnt(12) lgkmcnt(0)" ::: "memory"); // A(kk)+B-writes done
        __builtin_amdgcn_sched_barrier(0);
        __builtin_amdgcn_s_barrier();
        COMPUTE(buf);
        __builtin_amdgcn_s_barrier();
    }
    asm volatile("s_waitcnt vmcnt(4)" ::: "memory");      // rB(7) landed
    __builtin_amdgcn_sched_barrier(0);
    WRITEB(1);
    asm volatile("s_waitcnt vmcnt(0) lgkmcnt(0)" ::: "memory");
    __builtin_amdgcn_sched_barrier(0);
    __builtin_amdgcn_s_barrier();
    COMPUTE(1);                                           // tile 7

    const int dcol0 = nt * 128 + wc * 64;
    #pragma unroll
    for (int m = 0; m < 4; ++m) {
        #pragma unroll
        for (int n = 0; n < 4; ++n) {
            #pragma unroll
            for (int i = 0; i < 4; ++i) {
                int row = tok0 + wr * 64 + m * 16 + (lane >> 4) * 4 + i;
                int col = dcol0 + n * 16 + (lane & 15);
                Out[(size_t)row * DDIM + col] = acc[m][n][i];
            }
        }
    }
}

extern "C" void kernel_launch(void* const* d_in, const int* in_sizes, int n_in,
                              void* d_out, int out_size, void* d_ws, size_t ws_size,
                              hipStream_t stream) {
    const float* X   = (const float*)d_in[0];   // (T, D) fp32
    const float* S   = (const float*)d_in[1];   // (T, D/32) fp32
    const float* W13 = (const float*)d_in[4];   // (E, 2H, D) fp32
    const float* W2  = (const float*)d_in[5];   // (E, D, H) fp32
    float* Out = (float*)d_out;                 // (T, D) fp32

    // workspace: Hb bf16 (T*H) = 8 MiB.
    // Xb (T*D bf16 = 16 MiB) lives in d_out's first half: gemm1 consumes it,
    // then gemm2 overwrites all of d_out with the final fp32 output.
    __hip_bfloat16* Hb = (__hip_bfloat16*)d_ws;
    unsigned short* Xb = (unsigned short*)d_out;

    convert_x_kernel<<<2048, 256, 0, stream>>>(X, S, Xb);
    gemm1_silu_kernel<<<NE * 8 * 8, 256, 0, stream>>>(Xb, W13, Hb);
    gemm2_kernel<<<NE * 8 * 8, 256, 0, stream>>>(Hb, W2, Out);
}